// Round 6
// baseline (50.086 us; speedup 1.0000x reference)
//
#include <hip/hip_runtime.h>

#define MDIM  1024
#define KDIM1 512
#define NDIM  256
#define MB    32
#define NB    32
#define KB1   64
#define KB2   32

// ---------------- K1: h1 = min_plus(x, W1), hm = min_plus(x, Wm) ----------------
// Tiles: 32x32 out, K-step 64, double-buffered LDS, reg-staged (no global_load_lds
// builtin: staging is not the bottleneck, prefetch distance = full step).
// Thread (tx,ty): cols {2tx,2tx+1}, rows {2ty,2ty+1}, both paths. 8 f32 accs.
__global__ __launch_bounds__(256, 1) void k1_minplus(
    const float* __restrict__ x,  const float* __restrict__ W1,
    const float* __restrict__ Wm, float* __restrict__ h1, float* __restrict__ hm)
{
    const int t  = threadIdx.x;
    const int tx = t & 15, ty = t >> 4;
    const int nt = blockIdx.x & 7, mt = blockIdx.x >> 3;   // nt rides XCD round-robin
    const int row0 = mt * MB, col0 = nt * NB;

    __shared__ float xs [2][MB][KB1 + 4];   // [32][68]: bank(4m+k), row stride 272B (16B-aligned)
    __shared__ float w1s[2][KB1][NB + 4];   // [64][36]: bank(4k+n), row stride 144B (16B-aligned)
    __shared__ float wms[2][KB1][NB + 4];

    const int sr = t >> 3;            // 0..31: x-row / W k-row
    const int sq = (t & 7) << 2;      // 0,4,..,28: quad offset (x: k, W: n)

    const float* xg  = x  + (size_t)(row0 + sr) * KDIM1;
    const float* w1g = W1 + (size_t)sr * NDIM + col0 + sq;
    const float* wmg = Wm + (size_t)sr * NDIM + col0 + sq;

    float4 rx0, rx1, rw10, rw11, rwm0, rwm1;

    // prologue: stage step 0
    rx0  = *(const float4*)(xg + sq);
    rx1  = *(const float4*)(xg + sq + 32);
    rw10 = *(const float4*)(w1g);
    rw11 = *(const float4*)(w1g + (size_t)32 * NDIM);
    rwm0 = *(const float4*)(wmg);
    rwm1 = *(const float4*)(wmg + (size_t)32 * NDIM);
    *(float4*)&xs [0][sr][sq]      = rx0;
    *(float4*)&xs [0][sr][sq + 32] = rx1;
    *(float4*)&w1s[0][sr][sq]      = rw10;
    *(float4*)&w1s[0][sr + 32][sq] = rw11;
    *(float4*)&wms[0][sr][sq]      = rwm0;
    *(float4*)&wms[0][sr + 32][sq] = rwm1;
    __syncthreads();

    const float INF = __builtin_huge_valf();
    float2 a1[2], am[2];
    a1[0] = make_float2(INF, INF); a1[1] = make_float2(INF, INF);
    am[0] = make_float2(INF, INF); am[1] = make_float2(INF, INF);

    const int m0 = ty * 2, m1 = m0 + 1, n0 = tx * 2;

    int cur = 0;
    const int NSTEP = KDIM1 / KB1;   // 8
    for (int s = 0; s < NSTEP; ++s) {
        if (s + 1 < NSTEP) {         // issue next-step global loads (consumed post-compute)
            const int k0 = (s + 1) * KB1;
            rx0  = *(const float4*)(xg + k0 + sq);
            rx1  = *(const float4*)(xg + k0 + sq + 32);
            rw10 = *(const float4*)(w1g + (size_t)k0 * NDIM);
            rw11 = *(const float4*)(w1g + (size_t)(k0 + 32) * NDIM);
            rwm0 = *(const float4*)(wmg + (size_t)k0 * NDIM);
            rwm1 = *(const float4*)(wmg + (size_t)(k0 + 32) * NDIM);
        }
        #pragma unroll
        for (int kk = 0; kk < KB1; kk += 4) {
            const float4 xa = *(const float4*)&xs[cur][m0][kk];
            const float4 xb = *(const float4*)&xs[cur][m1][kk];
            const float xav[4] = {xa.x, xa.y, xa.z, xa.w};
            const float xbv[4] = {xb.x, xb.y, xb.z, xb.w};
            float2 w1v[4], wmv[4];
            #pragma unroll
            for (int u = 0; u < 4; ++u) {
                w1v[u] = *(const float2*)&w1s[cur][kk + u][n0];
                wmv[u] = *(const float2*)&wms[cur][kk + u][n0];
            }
            a1[0].x = fminf(a1[0].x, fminf(fminf(xav[0]+w1v[0].x, xav[1]+w1v[1].x),
                                           fminf(xav[2]+w1v[2].x, xav[3]+w1v[3].x)));
            a1[0].y = fminf(a1[0].y, fminf(fminf(xav[0]+w1v[0].y, xav[1]+w1v[1].y),
                                           fminf(xav[2]+w1v[2].y, xav[3]+w1v[3].y)));
            a1[1].x = fminf(a1[1].x, fminf(fminf(xbv[0]+w1v[0].x, xbv[1]+w1v[1].x),
                                           fminf(xbv[2]+w1v[2].x, xbv[3]+w1v[3].x)));
            a1[1].y = fminf(a1[1].y, fminf(fminf(xbv[0]+w1v[0].y, xbv[1]+w1v[1].y),
                                           fminf(xbv[2]+w1v[2].y, xbv[3]+w1v[3].y)));
            am[0].x = fminf(am[0].x, fminf(fminf(xav[0]+wmv[0].x, xav[1]+wmv[1].x),
                                           fminf(xav[2]+wmv[2].x, xav[3]+wmv[3].x)));
            am[0].y = fminf(am[0].y, fminf(fminf(xav[0]+wmv[0].y, xav[1]+wmv[1].y),
                                           fminf(xav[2]+wmv[2].y, xav[3]+wmv[3].y)));
            am[1].x = fminf(am[1].x, fminf(fminf(xbv[0]+wmv[0].x, xbv[1]+wmv[1].x),
                                           fminf(xbv[2]+wmv[2].x, xbv[3]+wmv[3].x)));
            am[1].y = fminf(am[1].y, fminf(fminf(xbv[0]+wmv[0].y, xbv[1]+wmv[1].y),
                                           fminf(xbv[2]+wmv[2].y, xbv[3]+wmv[3].y)));
        }
        if (s + 1 < NSTEP) {         // commit to the idle buffer
            const int nb = cur ^ 1;
            *(float4*)&xs [nb][sr][sq]      = rx0;
            *(float4*)&xs [nb][sr][sq + 32] = rx1;
            *(float4*)&w1s[nb][sr][sq]      = rw10;
            *(float4*)&w1s[nb][sr + 32][sq] = rw11;
            *(float4*)&wms[nb][sr][sq]      = rwm0;
            *(float4*)&wms[nb][sr + 32][sq] = rwm1;
        }
        __syncthreads();
        cur ^= 1;
    }

    float* h1p = h1 + (size_t)(row0 + m0) * NDIM + col0 + n0;
    float* hmp = hm + (size_t)(row0 + m0) * NDIM + col0 + n0;
    *(float2*)h1p          = a1[0];
    *(float2*)(h1p + NDIM) = a1[1];
    *(float2*)hmp          = am[0];
    *(float2*)(hmp + NDIM) = am[1];
}

// ------ K2: out = min( max_i(h1+W2)+b2 , max_i(hm+Ws)+bs ) ------
__global__ __launch_bounds__(256, 1) void k2_maxplus(
    const float* __restrict__ h1, const float* __restrict__ hm,
    const float* __restrict__ W2, const float* __restrict__ Ws,
    const float* __restrict__ b2, const float* __restrict__ bs,
    float* __restrict__ out)
{
    const int t  = threadIdx.x;
    const int tx = t & 15, ty = t >> 4;
    const int nt = blockIdx.x & 7, mt = blockIdx.x >> 3;
    const int row0 = mt * MB, col0 = nt * NB;

    __shared__ float ah1[2][MB][KB2 + 4];   // [32][36]
    __shared__ float ahm[2][MB][KB2 + 4];
    __shared__ float w2s[2][KB2][NB + 4];   // [32][36]
    __shared__ float wss[2][KB2][NB + 4];

    const int sr = t >> 3;
    const int sq = (t & 7) << 2;

    const float* h1g = h1 + (size_t)(row0 + sr) * NDIM;
    const float* hmg = hm + (size_t)(row0 + sr) * NDIM;
    const float* w2g = W2 + (size_t)sr * NDIM + col0 + sq;
    const float* wsg = Ws + (size_t)sr * NDIM + col0 + sq;

    float4 ra, rb, rw2, rws;

    ra  = *(const float4*)(h1g + sq);
    rb  = *(const float4*)(hmg + sq);
    rw2 = *(const float4*)(w2g);
    rws = *(const float4*)(wsg);
    *(float4*)&ah1[0][sr][sq] = ra;
    *(float4*)&ahm[0][sr][sq] = rb;
    *(float4*)&w2s[0][sr][sq] = rw2;
    *(float4*)&wss[0][sr][sq] = rws;
    __syncthreads();

    const float INF = __builtin_huge_valf();
    float2 c1[2], cm[2];
    c1[0] = make_float2(-INF, -INF); c1[1] = make_float2(-INF, -INF);
    cm[0] = make_float2(-INF, -INF); cm[1] = make_float2(-INF, -INF);

    const int m0 = ty * 2, m1 = m0 + 1, n0 = tx * 2;

    int cur = 0;
    const int NSTEP = NDIM / KB2;   // 8
    for (int s = 0; s < NSTEP; ++s) {
        if (s + 1 < NSTEP) {
            const int k0 = (s + 1) * KB2;
            ra  = *(const float4*)(h1g + k0 + sq);
            rb  = *(const float4*)(hmg + k0 + sq);
            rw2 = *(const float4*)(w2g + (size_t)k0 * NDIM);
            rws = *(const float4*)(wsg + (size_t)k0 * NDIM);
        }
        #pragma unroll
        for (int kk = 0; kk < KB2; kk += 4) {
            const float4 pa = *(const float4*)&ah1[cur][m0][kk];
            const float4 pb = *(const float4*)&ah1[cur][m1][kk];
            const float4 qa = *(const float4*)&ahm[cur][m0][kk];
            const float4 qb = *(const float4*)&ahm[cur][m1][kk];
            const float pav[4] = {pa.x, pa.y, pa.z, pa.w};
            const float pbv[4] = {pb.x, pb.y, pb.z, pb.w};
            const float qav[4] = {qa.x, qa.y, qa.z, qa.w};
            const float qbv[4] = {qb.x, qb.y, qb.z, qb.w};
            float2 w2v[4], wsv[4];
            #pragma unroll
            for (int u = 0; u < 4; ++u) {
                w2v[u] = *(const float2*)&w2s[cur][kk + u][n0];
                wsv[u] = *(const float2*)&wss[cur][kk + u][n0];
            }
            c1[0].x = fmaxf(c1[0].x, fmaxf(fmaxf(pav[0]+w2v[0].x, pav[1]+w2v[1].x),
                                           fmaxf(pav[2]+w2v[2].x, pav[3]+w2v[3].x)));
            c1[0].y = fmaxf(c1[0].y, fmaxf(fmaxf(pav[0]+w2v[0].y, pav[1]+w2v[1].y),
                                           fmaxf(pav[2]+w2v[2].y, pav[3]+w2v[3].y)));
            c1[1].x = fmaxf(c1[1].x, fmaxf(fmaxf(pbv[0]+w2v[0].x, pbv[1]+w2v[1].x),
                                           fmaxf(pbv[2]+w2v[2].x, pbv[3]+w2v[3].x)));
            c1[1].y = fmaxf(c1[1].y, fmaxf(fmaxf(pbv[0]+w2v[0].y, pbv[1]+w2v[1].y),
                                           fmaxf(pbv[2]+w2v[2].y, pbv[3]+w2v[3].y)));
            cm[0].x = fmaxf(cm[0].x, fmaxf(fmaxf(qav[0]+wsv[0].x, qav[1]+wsv[1].x),
                                           fmaxf(qav[2]+wsv[2].x, qav[3]+wsv[3].x)));
            cm[0].y = fmaxf(cm[0].y, fmaxf(fmaxf(qav[0]+wsv[0].y, qav[1]+wsv[1].y),
                                           fmaxf(qav[2]+wsv[2].y, qav[3]+wsv[3].y)));
            cm[1].x = fmaxf(cm[1].x, fmaxf(fmaxf(qbv[0]+wsv[0].x, qbv[1]+wsv[1].x),
                                           fmaxf(qbv[2]+wsv[2].x, qbv[3]+wsv[3].x)));
            cm[1].y = fmaxf(cm[1].y, fmaxf(fmaxf(qbv[0]+wsv[0].y, qbv[1]+wsv[1].y),
                                           fmaxf(qbv[2]+wsv[2].y, qbv[3]+wsv[3].y)));
        }
        if (s + 1 < NSTEP) {
            const int nb = cur ^ 1;
            *(float4*)&ah1[nb][sr][sq] = ra;
            *(float4*)&ahm[nb][sr][sq] = rb;
            *(float4*)&w2s[nb][sr][sq] = rw2;
            *(float4*)&wss[nb][sr][sq] = rws;
        }
        __syncthreads();
        cur ^= 1;
    }

    const float2 B2 = *(const float2*)&b2[col0 + n0];
    const float2 BS = *(const float2*)&bs[col0 + n0];
    float2 o0, o1;
    o0.x = fminf(c1[0].x + B2.x, cm[0].x + BS.x);
    o0.y = fminf(c1[0].y + B2.y, cm[0].y + BS.y);
    o1.x = fminf(c1[1].x + B2.x, cm[1].x + BS.x);
    o1.y = fminf(c1[1].y + B2.y, cm[1].y + BS.y);
    float* op = out + (size_t)(row0 + m0) * NDIM + col0 + n0;
    *(float2*)op          = o0;
    *(float2*)(op + NDIM) = o1;
}

extern "C" void kernel_launch(void* const* d_in, const int* in_sizes, int n_in,
                              void* d_out, int out_size, void* d_ws, size_t ws_size,
                              hipStream_t stream) {
    const float* x  = (const float*)d_in[0];
    const float* W1 = (const float*)d_in[1];
    const float* W2 = (const float*)d_in[2];
    const float* b2 = (const float*)d_in[3];
    const float* Wm = (const float*)d_in[4];
    const float* Ws = (const float*)d_in[5];
    const float* bs = (const float*)d_in[6];
    float* out = (float*)d_out;

    float* h1 = (float*)d_ws;                    // 1 MB
    float* hm = h1 + (size_t)MDIM * NDIM;        // 1 MB

    dim3 grid((MDIM / MB) * (NDIM / NB));        // 256 blocks
    dim3 block(256);
    k1_minplus<<<grid, block, 0, stream>>>(x, W1, Wm, h1, hm);
    k2_maxplus<<<grid, block, 0, stream>>>(h1, hm, W2, Ws, b2, bs, out);
}

// Round 7
// 33.378 us; speedup vs baseline: 1.5005x; 1.5005x over previous
//
#include <hip/hip_runtime.h>
#include <hip/hip_fp16.h>

#define BATCH   1024
#define IN_DIM  512
#define OUT_DIM 256
#define RB      4      // batch rows per block (grid = 256 = 1 block/CU)
#define KC      4      // k-chunks (threadIdx.y); 1024 threads = 16 waves = 4/SIMD

// Tropical block in packed-f16: half2 lanes carry (main path, shortcut path).
//   stage1: acc = pk_min over k of pk_add( dup(x[r][k]), (W1[k][j],Wm[k][j]) )
//   stage2: acc = pk_max over i of pk_add( (h1[r][i],hm[r][i]), (W2[i][j],Ws[i][j]) )
//   epilogue: unpack, +bias (f32), min-combine, store f32.
// One v_pk_add + one v_pk_min per (k,row) covers BOTH matmul paths.
// Weight stream: 0.75 MB/CU f16-packed (was 1.5 MB f32); b128 = 4 k-terms.

typedef unsigned int u32;

static __device__ __forceinline__ u32 pk_add(u32 a, u32 b) {
    u32 d; asm("v_pk_add_f16 %0, %1, %2" : "=v"(d) : "v"(a), "v"(b)); return d;
}
static __device__ __forceinline__ u32 pk_min(u32 a, u32 b) {
    u32 d; asm("v_pk_min_f16 %0, %1, %2" : "=v"(d) : "v"(a), "v"(b)); return d;
}
static __device__ __forceinline__ u32 pk_max(u32 a, u32 b) {
    u32 d; asm("v_pk_max_f16 %0, %1, %2" : "=v"(d) : "v"(a), "v"(b)); return d;
}
static __device__ __forceinline__ u32 packh2(float lo, float hi) {
    const unsigned short l = __half_as_ushort(__float2half_rn(lo));
    const unsigned short h = __half_as_ushort(__float2half_rn(hi));
    return (u32)l | ((u32)h << 16);
}
static __device__ __forceinline__ float h2lo(u32 v) {
    return __half2float(__ushort_as_half((unsigned short)(v & 0xffffu)));
}
static __device__ __forceinline__ float h2hi(u32 v) {
    return __half2float(__ushort_as_half((unsigned short)(v >> 16)));
}

// ---- pre-kernel: pack (W1,Wm) and (W2,Ws) into k-quad-blocked f16 tables ----
// wpk1[kq][j][e] = half2(W1[4kq+e][j], Wm[4kq+e][j])   (512x256 -> 512 KB)
// wpk2[iq][j][e] = half2(W2[4iq+e][j], Ws[4iq+e][j])   (256x256 -> 256 KB)
__global__ __launch_bounds__(256) void convert_weights(
    const float* __restrict__ W1, const float* __restrict__ Wm,
    const float* __restrict__ W2, const float* __restrict__ Ws,
    u32* __restrict__ wpk1, u32* __restrict__ wpk2)
{
    const int stride = gridDim.x * blockDim.x;
    for (int t = blockIdx.x * blockDim.x + threadIdx.x;
         t < IN_DIM * OUT_DIM; t += stride) {
        const int k = t >> 8, j = t & 255;               // coalesced reads
        wpk1[((k >> 2) << 10) + (j << 2) + (k & 3)] = packh2(W1[t], Wm[t]);
    }
    for (int t = blockIdx.x * blockDim.x + threadIdx.x;
         t < OUT_DIM * OUT_DIM; t += stride) {
        const int i = t >> 8, j = t & 255;
        wpk2[((i >> 2) << 10) + (j << 2) + (i & 3)] = packh2(W2[t], Ws[t]);
    }
}

// ---- main fused kernel ----
__global__ __launch_bounds__(1024, 1) void tropical_fused(
    const float* __restrict__ x,
    const u32*   __restrict__ wpk1,
    const u32*   __restrict__ wpk2,
    const float* __restrict__ b2,
    const float* __restrict__ bs,
    float* __restrict__ out)
{
    const int j    = threadIdx.x;                                  // 0..255
    const int c    = __builtin_amdgcn_readfirstlane(threadIdx.y);  // 0..3 wave-uniform
    const int tid  = c * OUT_DIM + j;                              // 0..1023
    const int row0 = blockIdx.x * RB;

    __shared__ u32 xs[RB][IN_DIM];        // 8 KB: dup'd-f16 x rows
    __shared__ u32 part[KC][RB][OUT_DIM]; // 16 KB: split-K partials (half2)
    __shared__ u32 hbuf[RB][OUT_DIM];     // 4 KB: reduced (h1,hm) half2

    // ---- stage x rows: f32 global (coalesced float2) -> dup'd f16 LDS ----
    {
        const float2 xf = *(const float2*)(x + (size_t)row0 * IN_DIM + 2 * tid);
        const u32 d0 = (u32)__half_as_ushort(__float2half_rn(xf.x)) * 0x10001u;
        const u32 d1 = (u32)__half_as_ushort(__float2half_rn(xf.y)) * 0x10001u;
        ((uint2*)xs)[tid] = make_uint2(d0, d1);
    }
    __syncthreads();

    // ================= stage 1: min-plus, chunk = 128 k =================
    u32 acc[RB];
    #pragma unroll
    for (int r = 0; r < RB; ++r) acc[r] = 0x7C007C00u;   // (+inf,+inf)

    const int kb = c * (IN_DIM / KC);
    #pragma unroll 8
    for (int kk = 0; kk < IN_DIM / KC; kk += 4) {
        const int k = kb + kk;
        const uint4 w = *(const uint4*)(wpk1 + ((size_t)(k >> 2) << 10) + (j << 2));
        #pragma unroll
        for (int r = 0; r < RB; ++r) {
            const uint4 xv = *(const uint4*)&xs[r][k];   // uniform b128
            acc[r] = pk_min(acc[r], pk_add(xv.x, w.x));
            acc[r] = pk_min(acc[r], pk_add(xv.y, w.y));
            acc[r] = pk_min(acc[r], pk_add(xv.z, w.z));
            acc[r] = pk_min(acc[r], pk_add(xv.w, w.w));
        }
    }
    #pragma unroll
    for (int r = 0; r < RB; ++r) part[c][r][j] = acc[r];
    __syncthreads();

    // ---- reduce1: pk_min over chunks -> hbuf[r][i] = (h1,hm) ----
    {
        const int r = tid >> 8, q = tid & 255;
        u32 v = part[0][r][q];
        #pragma unroll
        for (int cc = 1; cc < KC; ++cc) v = pk_min(v, part[cc][r][q]);
        hbuf[r][q] = v;
    }
    __syncthreads();

    // ================= stage 2: max-plus, chunk = 64 i =================
    u32 acc2[RB];
    #pragma unroll
    for (int r = 0; r < RB; ++r) acc2[r] = 0xFC00FC00u;  // (-inf,-inf)

    const int ib = c * (OUT_DIM / KC);
    #pragma unroll 8
    for (int ii = 0; ii < OUT_DIM / KC; ii += 4) {
        const int i = ib + ii;
        const uint4 w = *(const uint4*)(wpk2 + ((size_t)(i >> 2) << 10) + (j << 2));
        #pragma unroll
        for (int r = 0; r < RB; ++r) {
            const uint4 hv = *(const uint4*)&hbuf[r][i];  // uniform b128
            acc2[r] = pk_max(acc2[r], pk_add(hv.x, w.x));
            acc2[r] = pk_max(acc2[r], pk_add(hv.y, w.y));
            acc2[r] = pk_max(acc2[r], pk_add(hv.z, w.z));
            acc2[r] = pk_max(acc2[r], pk_add(hv.w, w.w));
        }
    }
    #pragma unroll
    for (int r = 0; r < RB; ++r) part[c][r][j] = acc2[r];
    __syncthreads();

    // ---- reduce2 + epilogue: pk_max over chunks, +bias f32, min, store ----
    {
        const int r = tid >> 8, q = tid & 255;
        u32 v = part[0][r][q];
        #pragma unroll
        for (int cc = 1; cc < KC; ++cc) v = pk_max(v, part[cc][r][q]);
        const float o = fminf(h2lo(v) + b2[q], h2hi(v) + bs[q]);
        out[(size_t)(row0 + r) * OUT_DIM + q] = o;
    }
}

extern "C" void kernel_launch(void* const* d_in, const int* in_sizes, int n_in,
                              void* d_out, int out_size, void* d_ws, size_t ws_size,
                              hipStream_t stream) {
    const float* x  = (const float*)d_in[0];
    const float* W1 = (const float*)d_in[1];
    const float* W2 = (const float*)d_in[2];
    const float* b2 = (const float*)d_in[3];
    const float* Wm = (const float*)d_in[4];
    const float* Ws = (const float*)d_in[5];
    const float* bs = (const float*)d_in[6];
    float* out = (float*)d_out;

    u32* wpk1 = (u32*)d_ws;                        // 512 KB
    u32* wpk2 = wpk1 + IN_DIM * OUT_DIM;           // 256 KB

    convert_weights<<<512, 256, 0, stream>>>(W1, Wm, W2, Ws, wpk1, wpk2);

    dim3 grid(BATCH / RB);        // 256 blocks = 1 per CU
    dim3 block(OUT_DIM, KC);      // 1024 threads = 16 waves = 4/SIMD
    tropical_fused<<<grid, block, 0, stream>>>(x, wpk1, wpk2, b2, bs, out);
}

// Round 8
// 31.703 us; speedup vs baseline: 1.5798x; 1.0528x over previous
//
#include <hip/hip_runtime.h>
#include <hip/hip_fp16.h>

typedef unsigned int u32;

#define IN_DIM  512
#define OUT_DIM 256
#define K1_RG   32     // rows per K1 block
#define K2_RG   16     // rows per K2 block

// packed-f16 tropical ops: half2 lanes carry (main path, shortcut path)
static __device__ __forceinline__ u32 pk_add(u32 a, u32 b) {
    u32 d; asm("v_pk_add_f16 %0, %1, %2" : "=v"(d) : "v"(a), "v"(b)); return d;
}
static __device__ __forceinline__ u32 pk_min(u32 a, u32 b) {
    u32 d; asm("v_pk_min_f16 %0, %1, %2" : "=v"(d) : "v"(a), "v"(b)); return d;
}
static __device__ __forceinline__ u32 pk_max(u32 a, u32 b) {
    u32 d; asm("v_pk_max_f16 %0, %1, %2" : "=v"(d) : "v"(a), "v"(b)); return d;
}
static __device__ __forceinline__ u32 packh2(float lo, float hi) {
    const unsigned short l = __half_as_ushort(__float2half_rn(lo));
    const unsigned short h = __half_as_ushort(__float2half_rn(hi));
    return (u32)l | ((u32)h << 16);
}
static __device__ __forceinline__ u32 duph(float v) {
    return (u32)__half_as_ushort(__float2half_rn(v)) * 0x10001u;
}
static __device__ __forceinline__ float h2lo(u32 v) {
    return __half2float(__ushort_as_half((unsigned short)(v & 0xffffu)));
}
static __device__ __forceinline__ float h2hi(u32 v) {
    return __half2float(__ushort_as_half((unsigned short)(v >> 16)));
}

// ---- convert: pack weights into j-slice-blocked f16-pair tables ----
// wpk1[((js*128+kq)*32+j)*4+e] = (W1[4kq+e][js*32+j], Wm[...])  -> 512 KB
// wpk2[((js* 64+iq)*32+j)*4+e] = (W2[4iq+e][js*32+j], Ws[...])  -> 256 KB
__global__ __launch_bounds__(256) void convert_weights(
    const float* __restrict__ W1, const float* __restrict__ Wm,
    const float* __restrict__ W2, const float* __restrict__ Ws,
    u32* __restrict__ wpk1, u32* __restrict__ wpk2)
{
    const int stride = gridDim.x * blockDim.x;
    for (int t = blockIdx.x * blockDim.x + threadIdx.x;
         t < IN_DIM * OUT_DIM; t += stride) {
        const int k = t >> 8, col = t & 255;                 // coalesced reads
        wpk1[(((col >> 5) * 128 + (k >> 2)) * 32 + (col & 31)) * 4 + (k & 3)]
            = packh2(W1[t], Wm[t]);
    }
    for (int t = blockIdx.x * blockDim.x + threadIdx.x;
         t < OUT_DIM * OUT_DIM; t += stride) {
        const int i = t >> 8, col = t & 255;
        wpk2[(((col >> 5) * 64 + (i >> 2)) * 32 + (col & 31)) * 4 + (i & 3)]
            = packh2(W2[t], Ws[t]);
    }
}

// ---- K1: h = packed (min_plus(x,W1), min_plus(x,Wm)), f16 ----
// grid 256 = 8 j-slices x 32 rowgroups; 512 threads = (j:32)x(rh:16),
// 2 rows/thread. LDS 128 KB. Inner loop: LDS+VALU only, NO barriers.
__global__ __launch_bounds__(512) void k1_minplus(
    const float* __restrict__ x, const u32* __restrict__ wpk1,
    u32* __restrict__ h)
{
    const int tid  = threadIdx.x;
    const int j    = tid & 31;
    const int rh   = tid >> 5;             // 0..15
    const int js   = blockIdx.x & 7;       // rides XCD round-robin
    const int rg   = blockIdx.x >> 3;
    const int row0 = rg * K1_RG;
    const int col  = js * 32 + j;

    __shared__ u32 wl[128 * 32 * 4];       // [kq][j][e]  64 KB
    __shared__ u32 xl[K1_RG][IN_DIM];      // dup'd f16   64 KB

    // stage weight slice: 4096 uint4, linear & coalesced
    {
        const uint4* src = (const uint4*)wpk1 + (size_t)js * 4096;
        uint4* dst = (uint4*)wl;
        #pragma unroll
        for (int s = 0; s < 8; ++s) dst[tid + s * 512] = src[tid + s * 512];
    }
    // stage x rows (f32 -> dup'd f16): 32 rows x 128 float4
    {
        const int r = tid >> 4;            // 0..31
        const int q = tid & 15;
        const float4* xr = (const float4*)(x + (size_t)(row0 + r) * IN_DIM);
        #pragma unroll
        for (int s = 0; s < 8; ++s) {
            const float4 f = xr[q + s * 16];
            uint4 d;
            d.x = duph(f.x); d.y = duph(f.y); d.z = duph(f.z); d.w = duph(f.w);
            *(uint4*)&xl[r][4 * (q + s * 16)] = d;
        }
    }
    __syncthreads();                        // the only barrier

    const int r0 = rh, r1 = rh + 16;
    u32 aA0 = 0x7C007C00u, aB0 = aA0, aA1 = aA0, aB1 = aA0;  // (+inf,+inf)
    #pragma unroll 4
    for (int kq = 0; kq < 128; ++kq) {
        const uint4 w  = *(const uint4*)&wl[(kq * 32 + j) * 4];  // per-lane 16B, conflict-free
        const uint4 x0 = *(const uint4*)&xl[r0][4 * kq];         // 2-addr broadcast
        const uint4 x1 = *(const uint4*)&xl[r1][4 * kq];
        aA0 = pk_min(aA0, pk_add(x0.x, w.x));
        aB0 = pk_min(aB0, pk_add(x0.y, w.y));
        aA0 = pk_min(aA0, pk_add(x0.z, w.z));
        aB0 = pk_min(aB0, pk_add(x0.w, w.w));
        aA1 = pk_min(aA1, pk_add(x1.x, w.x));
        aB1 = pk_min(aB1, pk_add(x1.y, w.y));
        aA1 = pk_min(aA1, pk_add(x1.z, w.z));
        aB1 = pk_min(aB1, pk_add(x1.w, w.w));
    }
    h[(size_t)(row0 + r0) * OUT_DIM + col] = pk_min(aA0, aB0);
    h[(size_t)(row0 + r1) * OUT_DIM + col] = pk_min(aA1, aB1);
}

// ---- K2: out = min( max_i(h1+W2)+b2 , max_i(hm+Ws)+bs ) ----
// grid 512 = 8 j-slices x 64 rowgroups (2 blocks/CU); 256 threads =
// (j:32)x(rh:8), 2 rows/thread. LDS 48 KB. Barrier-free inner loop.
__global__ __launch_bounds__(256) void k2_maxplus(
    const u32* __restrict__ h, const u32* __restrict__ wpk2,
    const float* __restrict__ b2, const float* __restrict__ bs,
    float* __restrict__ out)
{
    const int tid  = threadIdx.x;
    const int j    = tid & 31;
    const int rh   = tid >> 5;             // 0..7
    const int js   = blockIdx.x & 7;
    const int rg   = blockIdx.x >> 3;
    const int row0 = rg * K2_RG;
    const int col  = js * 32 + j;

    __shared__ u32 wl[64 * 32 * 4];        // [iq][j][e]  32 KB
    __shared__ u32 hl[K2_RG][OUT_DIM];     // packed h    16 KB

    {
        const uint4* src = (const uint4*)wpk2 + (size_t)js * 2048;
        uint4* dst = (uint4*)wl;
        #pragma unroll
        for (int s = 0; s < 8; ++s) dst[tid + s * 256] = src[tid + s * 256];
    }
    {
        const uint4* src = (const uint4*)(h + (size_t)row0 * OUT_DIM);
        uint4* dst = (uint4*)hl;
        #pragma unroll
        for (int s = 0; s < 4; ++s) dst[tid + s * 256] = src[tid + s * 256];
    }
    __syncthreads();

    const int r0 = rh, r1 = rh + 8;
    u32 aA0 = 0xFC00FC00u, aB0 = aA0, aA1 = aA0, aB1 = aA0;  // (-inf,-inf)
    #pragma unroll 4
    for (int iq = 0; iq < 64; ++iq) {
        const uint4 w  = *(const uint4*)&wl[(iq * 32 + j) * 4];
        const uint4 h0 = *(const uint4*)&hl[r0][4 * iq];
        const uint4 h1 = *(const uint4*)&hl[r1][4 * iq];
        aA0 = pk_max(aA0, pk_add(h0.x, w.x));
        aB0 = pk_max(aB0, pk_add(h0.y, w.y));
        aA0 = pk_max(aA0, pk_add(h0.z, w.z));
        aB0 = pk_max(aB0, pk_add(h0.w, w.w));
        aA1 = pk_max(aA1, pk_add(h1.x, w.x));
        aB1 = pk_max(aB1, pk_add(h1.y, w.y));
        aA1 = pk_max(aA1, pk_add(h1.z, w.z));
        aB1 = pk_max(aB1, pk_add(h1.w, w.w));
    }
    const u32 m0 = pk_max(aA0, aB0);
    const u32 m1 = pk_max(aA1, aB1);
    out[(size_t)(row0 + r0) * OUT_DIM + col] = fminf(h2lo(m0) + b2[col], h2hi(m0) + bs[col]);
    out[(size_t)(row0 + r1) * OUT_DIM + col] = fminf(h2lo(m1) + b2[col], h2hi(m1) + bs[col]);
}

extern "C" void kernel_launch(void* const* d_in, const int* in_sizes, int n_in,
                              void* d_out, int out_size, void* d_ws, size_t ws_size,
                              hipStream_t stream) {
    const float* x  = (const float*)d_in[0];
    const float* W1 = (const float*)d_in[1];
    const float* W2 = (const float*)d_in[2];
    const float* b2 = (const float*)d_in[3];
    const float* Wm = (const float*)d_in[4];
    const float* Ws = (const float*)d_in[5];
    const float* bs = (const float*)d_in[6];
    float* out = (float*)d_out;

    u32* wpk1 = (u32*)d_ws;                          // 512 KB
    u32* wpk2 = wpk1 + IN_DIM * OUT_DIM;             // 256 KB
    u32* h    = wpk2 + OUT_DIM * OUT_DIM;            // 1 MB packed h

    convert_weights<<<512, 256, 0, stream>>>(W1, Wm, W2, Ws, wpk1, wpk2);
    k1_minplus<<<256, 512, 0, stream>>>(x, wpk1, h);     // 8 js x 32 rowgroups
    k2_maxplus<<<512, 256, 0, stream>>>(h, wpk2, b2, bs, out);  // 8 js x 64 rowgroups
}